// Round 9
// baseline (330.622 us; speedup 1.0000x reference)
//
#include <hip/hip_runtime.h>

// Problem constants
#define D_  1024
#define S_  2048
#define B_  4
#define H_  16
#define HD_ 64
#define BS_ (B_*S_)   // 8192 rows

// GEMM tiling (m97 structure)
#define BM 128
#define BN 128
#define BK 32
#define NT (D_ / BK)   // 32 K-steps

typedef __attribute__((ext_vector_type(8))) short short8;   // 8 bf16 = 4 VGPRs
typedef __attribute__((ext_vector_type(4))) float floatx4;  // MFMA C/D
typedef __attribute__((ext_vector_type(4))) unsigned int uint4v;

typedef __attribute__((address_space(3))) unsigned int lds_uint;
typedef const __attribute__((address_space(1))) unsigned int glob_uint;

// Workspace layout (byte offsets), 72 MB total.
#define WS_XB ((size_t)0)            // 16 MB bf16 x
#define WS_WQ ((size_t)16 << 20)     // 2 MB bf16 Wq
#define WS_WK ((size_t)18 << 20)
#define WS_WV ((size_t)20 << 20)
#define WS_WO ((size_t)22 << 20)
#define WS_Q  ((size_t)24 << 20)     // 16 MB bf16 Q [b,h,s,hd]
#define WS_KK ((size_t)40 << 20)     // 16 MB bf16 K [b,h,s,hd]
#define WS_VT ((size_t)56 << 20)     // 16 MB bf16 V^T [b,h,hd,s]
#define WS_Y  WS_Q                   // y (fp32, 32 MB) overlays Q+K after attn

static __device__ __forceinline__ unsigned short f2bf(float f) {
  unsigned u = __builtin_bit_cast(unsigned, f);
  unsigned r = (u + 0x7fffu + ((u >> 16) & 1u)) >> 16;  // RNE
  return (unsigned short)r;
}

static __device__ __forceinline__ unsigned cvtpk_bf16(float lo, float hi) {
  unsigned r;
  asm("v_cvt_pk_bf16_f32 %0, %1, %2" : "=v"(r) : "v"(lo), "v"(hi));
  return r;
}

static __device__ __forceinline__ float exp2_fast(float x) {
  float r;
  asm("v_exp_f32 %0, %1" : "=v"(r) : "v"(x));   // D = 2^S0
  return r;
}

#define PSWAP(a, b) asm("v_permlane32_swap_b32 %0, %1" : "+v"(a), "+v"(b))

// ---------------------------------------------------------------------------
// Kernel 0: fp32 -> bf16 convert (RNE), 4 elements per thread.
// ---------------------------------------------------------------------------
__global__ __launch_bounds__(256) void cvt_f32_bf16(
    const float* __restrict__ src, unsigned short* __restrict__ dst, int n4)
{
  int i = blockIdx.x * 256 + threadIdx.x;
  if (i < n4) {
    float4 v = ((const float4*)src)[i];
    ushort4 o;
    o.x = f2bf(v.x); o.y = f2bf(v.y); o.z = f2bf(v.z); o.w = f2bf(v.w);
    ((ushort4*)dst)[i] = o;
  }
}

// ---------------------------------------------------------------------------
// Tiled GEMM mainloop (shared by gemm_qkv / gemm_out). m97 structure.
// ---------------------------------------------------------------------------
#define GEMM_MAINLOOP(Aptr, Bptr)                                              \
  __shared__ unsigned short lds[2][2][BM * BK];                                \
  const int tid  = threadIdx.x;                                                \
  const int wv   = tid >> 6;                                                   \
  const int lane = tid & 63;                                                   \
  const int c    = lane & 15;                                                  \
  const int quad = lane >> 4;                                                  \
  const int m0   = blockIdx.x * BM;                                            \
  const int n0   = blockIdx.y * BN;                                            \
  const int srow = lane >> 2;                                                  \
  const int scol = (lane & 3) * 8;                                             \
  const unsigned short* gA = (Aptr) + (size_t)(m0 + wv * 16 + srow) * D_ + scol;\
  const unsigned short* gB = (Bptr) + (size_t)(n0 + wv * 16 + srow) * D_ + scol;\
  const int lbase = (wv * 16) * BK;                                            \
  const int wr = (wv >> 1) * 64;                                               \
  const int wc = (wv & 1) * 64;                                                \
  floatx4 acc[4][4];                                                           \
  _Pragma("unroll")                                                            \
  for (int mi = 0; mi < 4; ++mi)                                               \
    _Pragma("unroll")                                                          \
    for (int ni = 0; ni < 4; ++ni) acc[mi][ni] = (floatx4){0.f,0.f,0.f,0.f};   \
  auto stage = [&](int buf, int t) {                                           \
    const size_t koff = (size_t)t * BK;                                        \
    _Pragma("unroll")                                                          \
    for (int j = 0; j < 2; ++j) {                                              \
      __builtin_amdgcn_global_load_lds(                                        \
          (glob_uint*)(gA + (size_t)j * 64 * D_ + koff),                       \
          (lds_uint*)&lds[buf][0][j * 64 * BK + lbase], 16, 0, 0);             \
      __builtin_amdgcn_global_load_lds(                                        \
          (glob_uint*)(gB + (size_t)j * 64 * D_ + koff),                       \
          (lds_uint*)&lds[buf][1][j * 64 * BK + lbase], 16, 0, 0);             \
    }                                                                          \
  };                                                                           \
  stage(0, 0);                                                                 \
  __syncthreads();                                                             \
  int cur = 0;                                                                 \
  for (int t = 0; t < NT; ++t) {                                               \
    if (t + 1 < NT) stage(cur ^ 1, t + 1);                                     \
    const unsigned short* LA = &lds[cur][0][0];                                \
    const unsigned short* LB = &lds[cur][1][0];                                \
    short8 af[4], bf[4];                                                       \
    _Pragma("unroll")                                                          \
    for (int i = 0; i < 4; ++i) {                                              \
      af[i] = *(const short8*)&LA[(wr + i * 16 + c) * BK + quad * 8];          \
      bf[i] = *(const short8*)&LB[(wc + i * 16 + c) * BK + quad * 8];          \
    }                                                                          \
    _Pragma("unroll")                                                          \
    for (int mi = 0; mi < 4; ++mi)                                             \
      _Pragma("unroll")                                                        \
      for (int ni = 0; ni < 4; ++ni)                                           \
        acc[mi][ni] = __builtin_amdgcn_mfma_f32_16x16x32_bf16(                 \
            af[mi], bf[ni], acc[mi][ni], 0, 0, 0);                             \
    __syncthreads();                                                           \
    cur ^= 1;                                                                  \
  }

// ---------------------------------------------------------------------------
// Kernel 1: QKV projection (tiled). mode = blockIdx.z:
//   0 -> Q [b,h,s,hd]; 1 -> K [b,h,s,hd]; 2 -> V^T [b,h,hd,s].
// ---------------------------------------------------------------------------
__global__ __launch_bounds__(256) void gemm_qkv(
    const unsigned short* __restrict__ X,
    const unsigned short* __restrict__ Wq, const float* __restrict__ bq,
    const unsigned short* __restrict__ Wk, const float* __restrict__ bk,
    const unsigned short* __restrict__ Wv, const float* __restrict__ bv,
    unsigned short* __restrict__ Qo, unsigned short* __restrict__ Ko,
    unsigned short* __restrict__ Vo)
{
  const int mode = blockIdx.z;
  const unsigned short* W = (mode == 0) ? Wq : ((mode == 1) ? Wk : Wv);
  const float* bias       = (mode == 0) ? bq : ((mode == 1) ? bk : bv);
  unsigned short* dst     = (mode == 0) ? Qo : ((mode == 1) ? Ko : Vo);

  GEMM_MAINLOOP(X, W)

  const int b = m0 >> 11;
  #pragma unroll
  for (int mi = 0; mi < 4; ++mi) {
    const int sb = (m0 & (S_ - 1)) + wr + mi * 16 + quad * 4;
    #pragma unroll
    for (int ni = 0; ni < 4; ++ni) {
      const int n   = n0 + wc + ni * 16 + c;
      const float bv_ = bias[n];
      const int h  = n >> 6;
      const int hd = n & 63;
      if (mode < 2) {
        size_t base = ((size_t)((b * H_ + h) * S_ + sb)) * HD_ + hd;
        #pragma unroll
        for (int r = 0; r < 4; ++r)
          dst[base + (size_t)r * HD_] = f2bf(acc[mi][ni][r] + bv_);
      } else {
        size_t base = ((size_t)((b * H_ + h) * HD_ + hd)) * S_ + sb;
        ushort4 o;
        o.x = f2bf(acc[mi][ni][0] + bv_);
        o.y = f2bf(acc[mi][ni][1] + bv_);
        o.z = f2bf(acc[mi][ni][2] + bv_);
        o.w = f2bf(acc[mi][ni][3] + bv_);
        *(ushort4*)&dst[base] = o;
      }
    }
  }
}

// ---------------------------------------------------------------------------
// Kernel 2 (v11): v10 + counted-vmcnt 2-deep pipeline (T3/T4).
// __syncthreads drained vmcnt(0) every iter -> staging latency exposed at
// each barrier. Now: raw s_barrier + "s_waitcnt vmcnt(5)" keeps the NEXT
// tile's 5 loads in flight across barriers. Mask is staged through the same
// global_load_lds path (width 4; all 4 waves write identical 256 B - benign)
// so the loop body has NO other VMEM ops and the vmcnt FIFO count is exact:
//   prologue: loadQ(4 loads); stage(t0)=5; stage(t1)=5
//   iter t:  vmcnt(5) [t<31] / vmcnt(0) [t=31]  -> tile-t loads landed
//            s_barrier; compute (LDS-only, lgkm-tracked); s_barrier
//            if (t+2<32) stage(buf t&1, t+2)    // 5 loads fly across barriers
// Everything else (swizzle, P/V mapping, ones-MFMA l-sum, exp2) identical
// to verified v10.
// ---------------------------------------------------------------------------
__global__ __launch_bounds__(256)
void attn_kernel(
    const unsigned short* __restrict__ Q, const unsigned short* __restrict__ K,
    const unsigned short* __restrict__ Vt, const int* __restrict__ mask,
    unsigned short* __restrict__ ctx)
{
  __shared__ unsigned short Kl[2][4096];  // 8 KB per buffer
  __shared__ unsigned short Vl[2][4096];
  __shared__ int            Ml[2][64];    // mask ints per tile (256 B/buf)

  const int wv   = threadIdx.x >> 6;
  const int lane = threadIdx.x & 63;
  const int c    = lane & 15;
  const int quad = lane >> 4;

  const int id = blockIdx.x;
  const int bh = (id & 7) + 8 * (id >> 7);   // bh%8 == id%8 (XCD co-location)
  const int qt = (id >> 3) & 15;
  const int b  = bh >> 4;
  const int h  = bh & 15;
  const int q0 = qt * 128 + wv * 32;         // 32 q-rows per wave

  const unsigned short* Qb = Q  + (size_t)bh * S_ * HD_;
  const unsigned short* Kb = K  + (size_t)bh * S_ * HD_;
  const unsigned short* Vb = Vt + (size_t)bh * HD_ * S_;
  const int* mrow = mask + b * S_;

  // Q as B-fragments (B-row j = q = lane&15) — issued BEFORE the staged
  // tiles, so these 4 loads are the oldest in the vmcnt FIFO and retire
  // with the first vmcnt(5) wait.
  short8 bQ[2][2];
  #pragma unroll
  for (int s = 0; s < 2; ++s) {
    const unsigned short* qrow = Qb + (size_t)(q0 + s * 16 + c) * HD_;
    bQ[s][0] = *(const short8*)(qrow + quad * 8);
    bQ[s][1] = *(const short8*)(qrow + 32 + quad * 8);
  }

  short8 ones;
  #pragma unroll
  for (int i = 0; i < 8; ++i) ones[i] = (short)0x3F80;  // bf16 1.0

  floatx4 acc[2][4], accl[2];
  #pragma unroll
  for (int s = 0; s < 2; ++s) {
    #pragma unroll
    for (int d = 0; d < 4; ++d) acc[s][d] = (floatx4){0.f, 0.f, 0.f, 0.f};
    accl[s] = (floatx4){0.f, 0.f, 0.f, 0.f};
  }

  const float SC = 0.125f * 1.44269504089f;  // (1/sqrt(64)) * log2(e)

  // Stage one 64-k tile: 2x K, 2x V (width 16, XOR-permuted source realizes
  // the swizzled layout in a linear write), 1x mask (width 4). 5 loads/wave.
  auto stageKV = [&](int buf, int kp0) {
    #pragma unroll
    for (int j = 0; j < 2; ++j) {
      const int Pb  = j * 256 + (wv << 6);
      const int P   = Pb + lane;
      const int row = P >> 3;
      const int c8  = (P & 7) ^ (row & 7);
      __builtin_amdgcn_global_load_lds(
          (glob_uint*)(Kb + (size_t)(kp0 + row) * HD_ + c8 * 8),
          (lds_uint*)&Kl[buf][Pb * 8], 16, 0, 0);
      __builtin_amdgcn_global_load_lds(
          (glob_uint*)(Vb + (size_t)row * S_ + kp0 + c8 * 8),
          (lds_uint*)&Vl[buf][Pb * 8], 16, 0, 0);
    }
    __builtin_amdgcn_global_load_lds(
        (glob_uint*)(mrow + kp0 + lane),
        (lds_uint*)&Ml[buf][0], 4, 0, 0);   // all waves write same data
  };

  stageKV(0, 0);
  stageKV(1, 64);

  for (int t = 0; t < S_ / 64; ++t) {
    const int kp0 = t * 64;
    const int cur = t & 1;

    if (t < S_ / 64 - 1)
      asm volatile("s_waitcnt vmcnt(5)" ::: "memory");
    else
      asm volatile("s_waitcnt vmcnt(0)" ::: "memory");
    __builtin_amdgcn_s_barrier();

    // mask words for this tile (from LDS, lgkm-tracked)
    int4 mk4[4];
    #pragma unroll
    for (int ct = 0; ct < 4; ++ct)
      mk4[ct] = *(const int4*)&Ml[cur][ct * 16 + quad * 4];

    // ---- QK^T (swapped) from swizzled LDS K tile ----
    floatx4 Cm[2][4];
    #pragma unroll
    for (int kt2 = 0; kt2 < 4; ++kt2) {
      const int krow = kt2 * 16 + c;
      const int sw   = krow & 7;
      short8 k0 = *(const short8*)&Kl[cur][krow * 64 + ((quad) ^ sw) * 8];
      short8 k1 = *(const short8*)&Kl[cur][krow * 64 + ((4 + quad) ^ sw) * 8];
      floatx4 z0 = {0.f,0.f,0.f,0.f}, z1 = {0.f,0.f,0.f,0.f};
      z0 = __builtin_amdgcn_mfma_f32_16x16x32_bf16(k0, bQ[0][0], z0, 0, 0, 0);
      z1 = __builtin_amdgcn_mfma_f32_16x16x32_bf16(k0, bQ[1][0], z1, 0, 0, 0);
      z0 = __builtin_amdgcn_mfma_f32_16x16x32_bf16(k1, bQ[0][1], z0, 0, 0, 0);
      z1 = __builtin_amdgcn_mfma_f32_16x16x32_bf16(k1, bQ[1][1], z1, 0, 0, 0);
      Cm[0][kt2] = z0;
      Cm[1][kt2] = z1;
    }

    // ---- mask + exp2 (static max) + pack to bf16 pairs ----
    unsigned w[2][4][2];
    #pragma unroll
    for (int ct = 0; ct < 4; ++ct) {
      const float mb0 = (mk4[ct].x == 0) ? -1e30f : 0.f;
      const float mb1 = (mk4[ct].y == 0) ? -1e30f : 0.f;
      const float mb2 = (mk4[ct].z == 0) ? -1e30f : 0.f;
      const float mb3 = (mk4[ct].w == 0) ? -1e30f : 0.f;
      #pragma unroll
      for (int s = 0; s < 2; ++s) {
        float p0 = exp2_fast(fmaf(Cm[s][ct][0], SC, mb0));
        float p1 = exp2_fast(fmaf(Cm[s][ct][1], SC, mb1));
        float p2 = exp2_fast(fmaf(Cm[s][ct][2], SC, mb2));
        float p3 = exp2_fast(fmaf(Cm[s][ct][3], SC, mb3));
        w[s][ct][0] = cvtpk_bf16(p0, p1);
        w[s][ct][1] = cvtpk_bf16(p2, p3);
      }
    }

    // ---- PV + l-sum: P B-frags in-register; V A-frags from swizzled LDS ----
    #pragma unroll
    for (int ch = 0; ch < 2; ++ch) {
      short8 pf[2];
      #pragma unroll
      for (int s = 0; s < 2; ++s) {
        unsigned a0 = w[s][2 * ch][0],     a1 = w[s][2 * ch][1];
        unsigned b0 = w[s][2 * ch + 1][0], b1 = w[s][2 * ch + 1][1];
        PSWAP(a0, b0);
        PSWAP(a1, b1);
        uint4v pw = {a0, a1, b0, b1};
        pf[s] = __builtin_bit_cast(short8, pw);
      }
      const int c0 = ch * 4 + (quad >> 1) * 2;   // first 16B chunk of 8B pair
      const int h0 = (quad & 1) * 4;             // 8B half within chunk (ushorts)
      #pragma unroll
      for (int dt = 0; dt < 4; ++dt) {
        const int vrow = dt * 16 + c;
        const int sw   = vrow & 7;
        uint2 vlo = *(const uint2*)&Vl[cur][vrow * 64 + ((c0)     ^ sw) * 8 + h0];
        uint2 vhi = *(const uint2*)&Vl[cur][vrow * 64 + ((c0 + 1) ^ sw) * 8 + h0];
        uint4v vw = {vlo.x, vlo.y, vhi.x, vhi.y};
        short8 vf = __builtin_bit_cast(short8, vw);
        acc[0][dt] = __builtin_amdgcn_mfma_f32_16x16x32_bf16(vf, pf[0], acc[0][dt], 0, 0, 0);
        acc[1][dt] = __builtin_amdgcn_mfma_f32_16x16x32_bf16(vf, pf[1], acc[1][dt], 0, 0, 0);
      }
      accl[0] = __builtin_amdgcn_mfma_f32_16x16x32_bf16(ones, pf[0], accl[0], 0, 0, 0);
      accl[1] = __builtin_amdgcn_mfma_f32_16x16x32_bf16(ones, pf[1], accl[1], 0, 0, 0);
    }

    __builtin_amdgcn_s_barrier();   // all waves done reading buf[t&1]
    if (t + 2 < S_ / 64) stageKV(cur, kp0 + 128);  // refill freed buffer
  }

  // ---- epilogue: accl already holds l (row-sum) for this lane's q-column --
  #pragma unroll
  for (int s = 0; s < 2; ++s) {
    const float inv = 1.f / accl[s][0];
    #pragma unroll
    for (int dt = 0; dt < 4; ++dt) {
      ushort4 o;
      o.x = f2bf(acc[s][dt][0] * inv);
      o.y = f2bf(acc[s][dt][1] * inv);
      o.z = f2bf(acc[s][dt][2] * inv);
      o.w = f2bf(acc[s][dt][3] * inv);
      *(ushort4*)&ctx[((size_t)(b * S_ + q0 + s * 16 + c)) * D_ +
                      h * HD_ + dt * 16 + quad * 4] = o;
    }
  }
}

// ---------------------------------------------------------------------------
// Kernel 3: out-proj + residual (tiled). y[m,n] = ctx@Wo.T + bo + x. y fp32.
// ---------------------------------------------------------------------------
__global__ __launch_bounds__(256) void gemm_out(
    const unsigned short* __restrict__ CTX, const unsigned short* __restrict__ W,
    const float* __restrict__ bo, const float* __restrict__ X,
    float* __restrict__ Y)
{
  GEMM_MAINLOOP(CTX, W)

  #pragma unroll
  for (int mi = 0; mi < 4; ++mi) {
    const int m = m0 + wr + mi * 16 + quad * 4;
    #pragma unroll
    for (int ni = 0; ni < 4; ++ni) {
      const int n = n0 + wc + ni * 16 + c;
      const float bias = bo[n];
      #pragma unroll
      for (int r = 0; r < 4; ++r)
        Y[(size_t)(m + r) * D_ + n] =
            acc[mi][ni][r] + bias + X[(size_t)(m + r) * D_ + n];
    }
  }
}

// ---------------------------------------------------------------------------
// Kernel 4: LayerNorm over last dim (1024). y fp32 in; OUTPUT FP32.
// ---------------------------------------------------------------------------
__global__ __launch_bounds__(256) void ln_kernel(
    const float* __restrict__ Y, const float* __restrict__ gamma,
    const float* __restrict__ beta, float* __restrict__ out)
{
  __shared__ float red[2][4];
  const int row  = blockIdx.x;
  const int tid  = threadIdx.x;
  const int wv   = tid >> 6;
  const int lane = tid & 63;
  const float* y = Y + (size_t)row * D_;

  float v[4];
  float sum = 0.f, sumsq = 0.f;
  #pragma unroll
  for (int i = 0; i < 4; ++i) {
    v[i] = y[tid + i * 256];
    sum += v[i];
    sumsq += v[i] * v[i];
  }
  #pragma unroll
  for (int off = 32; off > 0; off >>= 1) {
    sum   += __shfl_down(sum, off, 64);
    sumsq += __shfl_down(sumsq, off, 64);
  }
  if (lane == 0) { red[0][wv] = sum; red[1][wv] = sumsq; }
  __syncthreads();
  sum   = red[0][0] + red[0][1] + red[0][2] + red[0][3];
  sumsq = red[1][0] + red[1][1] + red[1][2] + red[1][3];

  const float mu   = sum * (1.f / D_);
  const float var  = sumsq * (1.f / D_) - mu * mu;
  const float rstd = rsqrtf(var + 1e-5f);

  #pragma unroll
  for (int i = 0; i < 4; ++i) {
    const int col = tid + i * 256;
    out[(size_t)row * D_ + col] = (v[i] - mu) * rstd * gamma[col] + beta[col];
  }
}

// ---------------------------------------------------------------------------
extern "C" void kernel_launch(void* const* d_in, const int* in_sizes, int n_in,
                              void* d_out, int out_size, void* d_ws, size_t ws_size,
                              hipStream_t stream) {
  const float* x     = (const float*)d_in[0];
  const int*   mask  = (const int*)d_in[1];
  const float* Wq    = (const float*)d_in[2];
  const float* bq    = (const float*)d_in[3];
  const float* Wk    = (const float*)d_in[4];
  const float* bk    = (const float*)d_in[5];
  const float* Wv    = (const float*)d_in[6];
  const float* bv    = (const float*)d_in[7];
  const float* Wo    = (const float*)d_in[8];
  const float* bo    = (const float*)d_in[9];
  const float* gamma = (const float*)d_in[10];
  const float* beta  = (const float*)d_in[11];

  char* ws = (char*)d_ws;
  unsigned short* xb    = (unsigned short*)(ws + WS_XB);
  unsigned short* wqb   = (unsigned short*)(ws + WS_WQ);
  unsigned short* wkb   = (unsigned short*)(ws + WS_WK);
  unsigned short* wvb   = (unsigned short*)(ws + WS_WV);
  unsigned short* wob   = (unsigned short*)(ws + WS_WO);
  unsigned short* q_ws  = (unsigned short*)(ws + WS_Q);
  unsigned short* k_ws  = (unsigned short*)(ws + WS_KK);
  unsigned short* vt_ws = (unsigned short*)(ws + WS_VT);
  float*          y_ws  = (float*)(ws + WS_Y);
  unsigned short* ctx   = (unsigned short*)d_out;

  const int nx4 = (BS_ * D_) / 4;
  const int nw4 = (D_ * D_) / 4;
  cvt_f32_bf16<<<(nx4 + 255) / 256, 256, 0, stream>>>(x,  xb,  nx4);
  cvt_f32_bf16<<<(nw4 + 255) / 256, 256, 0, stream>>>(Wq, wqb, nw4);
  cvt_f32_bf16<<<(nw4 + 255) / 256, 256, 0, stream>>>(Wk, wkb, nw4);
  cvt_f32_bf16<<<(nw4 + 255) / 256, 256, 0, stream>>>(Wv, wvb, nw4);
  cvt_f32_bf16<<<(nw4 + 255) / 256, 256, 0, stream>>>(Wo, wob, nw4);

  gemm_qkv<<<dim3(BS_ / BM, D_ / BN, 3), 256, 0, stream>>>(
      xb, wqb, bq, wkb, bk, wvb, bv, q_ws, k_ws, vt_ws);

  attn_kernel<<<dim3(16 * 64), 256, 0, stream>>>(   // 1024 blocks, swizzled
      q_ws, k_ws, vt_ws, mask, ctx);

  gemm_out<<<dim3(BS_ / BM, D_ / BN), 256, 0, stream>>>(
      ctx, wob, bo, x, y_ws);

  ln_kernel<<<BS_, 256, 0, stream>>>(y_ws, gamma, beta, (float*)d_out);
}